// Round 13
// baseline (79.156 us; speedup 1.0000x reference)
//
#include <hip/hip_runtime.h>

// Memristor dense fwd. q = max_w/9 enters linearly:
//   y[b,j] = 0.5*[ A + biasA + q*(B + biasB) ]
//   A = sum_r s*(wp*t^gp - wn*t^gn),  B = sum_r s*(t^gp - t^gn)
//   biasA = bp*n_pos - bn*n_neg, biasB = n_pos - n_neg  (bias row t=2 -> t^g = n)
// t = max(2|x|,1e-12), s = sign(x), L = log2(t), g = log2(n_param).
// Inner loop (wd = wp-wn staged): u = ep-en; B += s*u; A += s*(wp*u + wd*en).
//
// R13: SINGLE compute dispatch (R10 main verbatim) + in-kernel tail:
//  - all 1024 blocks co-resident (4/CU); producers: partials + slot + release-add
//  - bz==15 block per tile: spin acnt==1024 (bounded), acquire, q, z-reduce, out
//  - 8-byte hipMemsetAsync zeroes the counter each call (handles junk/poison/replays)

#define N_IN 1024
#define N_OUT 512
#define NB 128
#define Z 16            // r-split across grid.z (64 rows per block)
#define RPC 32          // rows per staged chunk (2 chunks per block)
#define JT 64
#define BT 16

typedef float v2f __attribute__((ext_vector_type(2)));

// ws layout: uint[0] = acnt (zeroed per call); float[16..143] = 128 max slots;
//   A partials at AOFF [Z][NB][N_OUT] = 4 MiB; B partials at BOFF = 4 MiB.
#define AOFF 1024
#define BOFF (1024 + Z * NB * N_OUT)

__launch_bounds__(256, 4)
__global__ void memristor_one(const float* __restrict__ x,
                              const float* __restrict__ wp,
                              const float* __restrict__ wn,
                              const float* __restrict__ bp,
                              const float* __restrict__ bn,
                              const float* __restrict__ npar,
                              float* __restrict__ ws,
                              float* __restrict__ out) {
    // Wg[r][arr][grp][4]: arr 0=wp, 1=wd=wp-wn, 2=gp, 3=gn; grp XOR-swizzled by r
    __shared__ float Wg[RPC][4][16][4];   // 32 KiB
    __shared__ float Lx[RPC][BT][2];      // 4 KiB: (L, s), r-major

    const int tid = threadIdx.x;
    const int jx = blockIdx.x, by = blockIdx.y, bz = blockIdx.z;
    const int j0 = jx * JT;
    const int b0 = by * BT;
    unsigned* acnt = (unsigned*)ws;
    float* slots = ws + 16;

    const int tj4 = tid & 15;       // j group (4 cols)
    const int bl  = tid >> 4;       // 0..15: b row

    v2f accA01 = {0.f, 0.f}, accA23 = {0.f, 0.f};
    v2f accB01 = {0.f, 0.f}, accB23 = {0.f, 0.f};
    float m_w = 0.0f;               // tile weight max (free: data already in regs)

    for (int c = 0; c < 2; ++c) {
        const int rbase = bz * 64 + c * RPC;
        __syncthreads();   // protect LDS reuse across chunks
        {   // stage x: 16 b x 32 r; 2 consecutive r per thread
            int rq = tid & 15;
            float2 v = *(const float2*)&x[(b0 + bl) * N_IN + rbase + rq * 2];
            float vv[2] = {v.x, v.y};
            #pragma unroll
            for (int k = 0; k < 2; ++k) {
                float val = vv[k];
                float s = (val > 0.f) ? 1.f : ((val < 0.f) ? -1.f : 0.f);
                float t = fmaxf(2.f * fabsf(val), 1e-12f);
                Lx[rq * 2 + k][bl][0] = __builtin_amdgcn_logf(t);   // log2
                Lx[rq * 2 + k][bl][1] = s;
            }
        }
        {   // stage weights (wp, wd) + gammas: 32 r-rows x 64 j-cols; 8 j per thread
            int rr = tid >> 3;          // 0..31
            int cg = tid & 7;           // 0..7
            int pg0 = (2 * cg) ^ (rr & 15);
            int pg1 = (2 * cg + 1) ^ (rr & 15);
            {
                const float* prow = &wp[(rbase + rr) * N_OUT + j0 + cg * 8];
                const float* nrow = &wn[(rbase + rr) * N_OUT + j0 + cg * 8];
                float4 pa = *(const float4*)&prow[0];
                float4 pb = *(const float4*)&prow[4];
                float4 na = *(const float4*)&nrow[0];
                float4 nb = *(const float4*)&nrow[4];
                *(float4*)&Wg[rr][0][pg0][0] = pa;
                *(float4*)&Wg[rr][0][pg1][0] = pb;
                *(float4*)&Wg[rr][1][pg0][0] = make_float4(pa.x - na.x, pa.y - na.y,
                                                           pa.z - na.z, pa.w - na.w);
                *(float4*)&Wg[rr][1][pg1][0] = make_float4(pb.x - nb.x, pb.y - nb.y,
                                                           pb.z - nb.z, pb.w - nb.w);
                m_w = fmaxf(m_w, fmaxf(fmaxf(pa.x, pa.y), fmaxf(pa.z, pa.w)));
                m_w = fmaxf(m_w, fmaxf(fmaxf(pb.x, pb.y), fmaxf(pb.z, pb.w)));
                m_w = fmaxf(m_w, fmaxf(fmaxf(na.x, na.y), fmaxf(na.z, na.w)));
                m_w = fmaxf(m_w, fmaxf(fmaxf(nb.x, nb.y), fmaxf(nb.z, nb.w)));
            }
            {
                const float* grow = &npar[(rbase + rr) * (2 * N_OUT) + 2 * j0 + cg * 16];
                float4 f0 = *(const float4*)&grow[0];    // p0 n0 p1 n1
                float4 f1 = *(const float4*)&grow[4];    // p2 n2 p3 n3
                float4 f2 = *(const float4*)&grow[8];
                float4 f3 = *(const float4*)&grow[12];
                *(float4*)&Wg[rr][2][pg0][0] = make_float4(
                    __builtin_amdgcn_logf(f0.x), __builtin_amdgcn_logf(f0.z),
                    __builtin_amdgcn_logf(f1.x), __builtin_amdgcn_logf(f1.z));
                *(float4*)&Wg[rr][3][pg0][0] = make_float4(
                    __builtin_amdgcn_logf(f0.y), __builtin_amdgcn_logf(f0.w),
                    __builtin_amdgcn_logf(f1.y), __builtin_amdgcn_logf(f1.w));
                *(float4*)&Wg[rr][2][pg1][0] = make_float4(
                    __builtin_amdgcn_logf(f2.x), __builtin_amdgcn_logf(f2.z),
                    __builtin_amdgcn_logf(f3.x), __builtin_amdgcn_logf(f3.z));
                *(float4*)&Wg[rr][3][pg1][0] = make_float4(
                    __builtin_amdgcn_logf(f2.y), __builtin_amdgcn_logf(f2.w),
                    __builtin_amdgcn_logf(f3.y), __builtin_amdgcn_logf(f3.w));
            }
        }
        __syncthreads();

        #pragma unroll 8
        for (int r = 0; r < RPC; ++r) {
            const float4* wrow = (const float4*)&Wg[r][0][tj4 ^ (r & 15)][0];
            float4 w_p = wrow[0];
            float4 w_d = wrow[16];
            float4 g_p = wrow[32];
            float4 g_n = wrow[48];
            float2 Ls = *(const float2*)&Lx[r][bl][0];
            const float L = Ls.x, s = Ls.y;

            v2f wp01 = {w_p.x, w_p.y}, wp23 = {w_p.z, w_p.w};
            v2f wd01 = {w_d.x, w_d.y}, wd23 = {w_d.z, w_d.w};
            v2f gp01 = {g_p.x, g_p.y}, gp23 = {g_p.z, g_p.w};
            v2f gn01 = {g_n.x, g_n.y}, gn23 = {g_n.z, g_n.w};

            v2f ap01 = L * gp01, ap23 = L * gp23;     // v_pk_mul
            v2f an01 = L * gn01, an23 = L * gn23;
            v2f ep01, ep23, en01, en23;
            ep01.x = __builtin_amdgcn_exp2f(ap01.x); ep01.y = __builtin_amdgcn_exp2f(ap01.y);
            ep23.x = __builtin_amdgcn_exp2f(ap23.x); ep23.y = __builtin_amdgcn_exp2f(ap23.y);
            en01.x = __builtin_amdgcn_exp2f(an01.x); en01.y = __builtin_amdgcn_exp2f(an01.y);
            en23.x = __builtin_amdgcn_exp2f(an23.x); en23.y = __builtin_amdgcn_exp2f(an23.y);

            v2f u01 = ep01 - en01, u23 = ep23 - en23; // v_pk_add
            accB01 += s * u01;                        // v_pk_fma (s broadcast)
            accB23 += s * u23;
            v2f v01 = wp01 * u01 + wd01 * en01;       // pk_mul + pk_fma
            v2f v23 = wp23 * u23 + wd23 * en23;
            accA01 += s * v01;
            accA23 += s * v23;
        }
    }

    // ---- write A/B partials (coalesced float4) ----
    {
        size_t base = (size_t)bz * (NB * N_OUT) + (b0 + bl) * N_OUT + j0 + tj4 * 4;
        *(float4*)&ws[AOFF + base] = make_float4(accA01.x, accA01.y, accA23.x, accA23.y);
        *(float4*)&ws[BOFF + base] = make_float4(accB01.x, accB01.y, accB23.x, accB23.y);
    }

    __syncthreads();   // partials issued by all threads; Lx free for aliasing
    if (by == 0) {     // tile weight-max slot (same weights for all by)
        float* qred = &Lx[0][0][0];
        #pragma unroll
        for (int off = 32; off; off >>= 1) m_w = fmaxf(m_w, __shfl_xor(m_w, off));
        if ((tid & 63) == 0) qred[tid >> 6] = m_w;
        __syncthreads();
        if (tid == 0)
            slots[jx * Z + bz] = fmaxf(fmaxf(qred[0], qred[1]), fmaxf(qred[2], qred[3]));
    }

    if (tid == 0) {
        __threadfence();   // partials + slot visible before the arrival tick
        __hip_atomic_fetch_add(acnt, 1u, __ATOMIC_RELEASE, __HIP_MEMORY_SCOPE_AGENT);
    }

    if (bz != Z - 1) return;

    // ================= tail: this block combines tile (jx, by) =================
    if (tid == 0) {
        while (__hip_atomic_load(acnt, __ATOMIC_RELAXED, __HIP_MEMORY_SCOPE_AGENT) < 1024u)
            __builtin_amdgcn_s_sleep(2);
    }
    __syncthreads();
    __builtin_amdgcn_fence(__ATOMIC_ACQUIRE, "agent");   // plain loads below see all partials

    float q;
    {
        float mm = (tid < 128) ? slots[tid] : 0.0f;
        float2 a2 = ((const float2*)bp)[tid];
        float2 b2 = ((const float2*)bn)[tid];
        mm = fmaxf(mm, fmaxf(fmaxf(a2.x, a2.y), fmaxf(b2.x, b2.y)));
        #pragma unroll
        for (int off = 32; off; off >>= 1) mm = fmaxf(mm, __shfl_xor(mm, off));
        float* qs = &Lx[0][0][0];
        __syncthreads();
        if ((tid & 63) == 0) qs[tid >> 6] = mm;
        __syncthreads();
        q = fmaxf(fmaxf(qs[0], qs[1]), fmaxf(qs[2], qs[3])) * (1.0f / 9.0f);
    }

    {   // z-reduce + bias + combine: 256 threads x 1 float4 = 16b x 64j tile
        int bb = tid >> 4, j4 = tid & 15;
        const float* colA = ws + AOFF + (b0 + bb) * N_OUT + j0 + j4 * 4;
        const float* colB = ws + BOFF + (b0 + bb) * N_OUT + j0 + j4 * 4;
        float ax = 0.f, ay = 0.f, az = 0.f, aw = 0.f;
        float bx = 0.f, byv = 0.f, bzv = 0.f, bw = 0.f;
        #pragma unroll
        for (int z = 0; z < Z; ++z) {
            float4 va = *(const float4*)(colA + (size_t)z * (NB * N_OUT));
            float4 vb = *(const float4*)(colB + (size_t)z * (NB * N_OUT));
            ax += va.x; ay += va.y; az += va.z; aw += va.w;
            bx += vb.x; byv += vb.y; bzv += vb.z; bw += vb.w;
        }
        int j = j0 + j4 * 4;
        float4 bpv = *(const float4*)&bp[j];
        float4 bnv = *(const float4*)&bn[j];
        const float* nrow = &npar[N_IN * (2 * N_OUT) + 2 * j];
        float4 n0 = *(const float4*)&nrow[0];     // (np0,nn0,np1,nn1)
        float4 n1 = *(const float4*)&nrow[4];     // (np2,nn2,np3,nn3)
        float y0 = 0.5f * (ax + bpv.x * n0.x - bnv.x * n0.y + q * (bx  + n0.x - n0.y));
        float y1 = 0.5f * (ay + bpv.y * n0.z - bnv.y * n0.w + q * (byv + n0.z - n0.w));
        float y2 = 0.5f * (az + bpv.z * n1.x - bnv.z * n1.y + q * (bzv + n1.x - n1.y));
        float y3 = 0.5f * (aw + bpv.w * n1.z - bnv.w * n1.w + q * (bw  + n1.z - n1.w));
        *(float4*)&out[(b0 + bb) * N_OUT + j] = make_float4(y0, y1, y2, y3);
    }
}

extern "C" void kernel_launch(void* const* d_in, const int* in_sizes, int n_in,
                              void* d_out, int out_size, void* d_ws, size_t ws_size,
                              hipStream_t stream) {
    const float* x    = (const float*)d_in[0];
    const float* wp   = (const float*)d_in[1];
    const float* wn   = (const float*)d_in[2];
    const float* bp   = (const float*)d_in[3];
    const float* bn   = (const float*)d_in[4];
    const float* npar = (const float*)d_in[5];
    float* out = (float*)d_out;
    float* ws  = (float*)d_ws;   // counter + 128 slots + 8 MiB A/B partials

    hipMemsetAsync(d_ws, 0, 8, stream);   // zero arrival counter (graph-capturable)

    dim3 grid(N_OUT / JT, NB / BT, Z);   // (8,8,16) = 1024 blocks, 4/CU -> all co-resident
    memristor_one<<<grid, 256, 0, stream>>>(x, wp, wn, bp, bn, npar, ws, out);
}

// Round 14
// 38.267 us; speedup vs baseline: 2.0685x; 2.0685x over previous
//
#include <hip/hip_runtime.h>

// Memristor dense fwd. q = max_w/9 enters linearly:
//   y[b,j] = 0.5*[ A + biasA + q*(B + biasB) ]
//   A = sum_r s*(wp*t^gp - wn*t^gn),  B = sum_r s*(t^gp - t^gn)
//   biasA = bp*n_pos - bn*n_neg, biasB = n_pos - n_neg  (bias row t=2 -> t^g = n)
// t = max(2|x|,1e-12), s = sign(x), L = log2(t), g = log2(n_param).
// Inner loop (wd = wp-wn staged): u = ep-en; B += s*u; A += s*(wp*u + wd*en).
// R14: clean occupancy experiment. JT 64->32 (J-split, not Z/B-split):
//   grid (16,8,16)=2048 blocks; partial volume and weight-staging redundancy
//   IDENTICAL to R10; LDS 20 KiB; launch_bounds(256,8) -> 32 waves/CU.

#define N_IN 1024
#define N_OUT 512
#define NB 128
#define Z 16            // r-split across grid.z (64 rows per block)
#define RPC 32          // rows per staged chunk (2 chunks per block)
#define JT 32
#define BT 16

typedef float v2f __attribute__((ext_vector_type(2)));

// ws float layout: [0..255] tile-max slots (slot = jx*16+bz, 256 used);
//   A partials at AOFF: [Z][NB][N_OUT] = 4 MiB; B partials at BOFF: 4 MiB.
#define AOFF 1024
#define BOFF (1024 + Z * NB * N_OUT)

__launch_bounds__(256, 8)
__global__ void memristor_mainAB(const float* __restrict__ x,
                                 const float* __restrict__ wp,
                                 const float* __restrict__ wn,
                                 const float* __restrict__ npar,
                                 float* __restrict__ ws) {
    // Wg[r][arr][grp][4]: arr 0=wp, 1=wd=wp-wn, 2=gp, 3=gn; grp (8) XOR-swizzled by r&7
    __shared__ float Wg[RPC][4][8][4];    // 16 KiB
    __shared__ float Lx[RPC][BT][2];      // 4 KiB: (L, s), r-major (broadcast reads)

    const int tid = threadIdx.x;
    const int jx = blockIdx.x, by = blockIdx.y, bz = blockIdx.z;
    const int j0 = jx * JT;
    const int b0 = by * BT;

    const int tj2 = tid & 15;       // j pair index: j = j0 + tj2*2 (+0/1)
    const int bl  = tid >> 4;       // 0..15: b row
    const int g8  = tj2 >> 1;       // group (0..7)
    const int sub = (tj2 & 1) * 2;  // float2 within group

    v2f accA = {0.f, 0.f};
    v2f accB = {0.f, 0.f};
    float m_w = 0.0f;               // tile weight max (free: data already in regs)

    for (int c = 0; c < 2; ++c) {
        const int rbase = bz * 64 + c * RPC;
        __syncthreads();   // protect LDS reuse across chunks
        {   // stage x: 16 b x 32 r; 2 consecutive r per thread
            int rq = tid & 15;
            float2 v = *(const float2*)&x[(b0 + bl) * N_IN + rbase + rq * 2];
            float vv[2] = {v.x, v.y};
            #pragma unroll
            for (int k = 0; k < 2; ++k) {
                float val = vv[k];
                float s = (val > 0.f) ? 1.f : ((val < 0.f) ? -1.f : 0.f);
                float t = fmaxf(2.f * fabsf(val), 1e-12f);
                Lx[rq * 2 + k][bl][0] = __builtin_amdgcn_logf(t);   // log2
                Lx[rq * 2 + k][bl][1] = s;
            }
        }
        {   // stage weights (wp, wd) + gammas: 32 r-rows x 32 j-cols; 4 j per thread
            int rr = tid >> 3;          // 0..31
            int cg = tid & 7;           // 0..7 (4-col group)
            int pg = cg ^ (rr & 7);     // XOR swizzle
            {
                const float* prow = &wp[(rbase + rr) * N_OUT + j0 + cg * 4];
                const float* nrow = &wn[(rbase + rr) * N_OUT + j0 + cg * 4];
                float4 pa = *(const float4*)&prow[0];
                float4 na = *(const float4*)&nrow[0];
                *(float4*)&Wg[rr][0][pg][0] = pa;
                *(float4*)&Wg[rr][1][pg][0] = make_float4(pa.x - na.x, pa.y - na.y,
                                                          pa.z - na.z, pa.w - na.w);
                m_w = fmaxf(m_w, fmaxf(fmaxf(pa.x, pa.y), fmaxf(pa.z, pa.w)));
                m_w = fmaxf(m_w, fmaxf(fmaxf(na.x, na.y), fmaxf(na.z, na.w)));
            }
            {
                const float* grow = &npar[(rbase + rr) * (2 * N_OUT) + 2 * j0 + cg * 8];
                float4 f0 = *(const float4*)&grow[0];    // p0 n0 p1 n1
                float4 f1 = *(const float4*)&grow[4];    // p2 n2 p3 n3
                *(float4*)&Wg[rr][2][pg][0] = make_float4(
                    __builtin_amdgcn_logf(f0.x), __builtin_amdgcn_logf(f0.z),
                    __builtin_amdgcn_logf(f1.x), __builtin_amdgcn_logf(f1.z));
                *(float4*)&Wg[rr][3][pg][0] = make_float4(
                    __builtin_amdgcn_logf(f0.y), __builtin_amdgcn_logf(f0.w),
                    __builtin_amdgcn_logf(f1.y), __builtin_amdgcn_logf(f1.w));
            }
        }
        __syncthreads();

        #pragma unroll 8
        for (int r = 0; r < RPC; ++r) {
            const float* wbase = &Wg[r][0][g8 ^ (r & 7)][sub];
            v2f w_p = *(const v2f*)&wbase[0];
            v2f w_d = *(const v2f*)&wbase[32];    // arr stride = 8 grp * 4 = 32 floats
            v2f g_p = *(const v2f*)&wbase[64];
            v2f g_n = *(const v2f*)&wbase[96];
            float2 Ls = *(const float2*)&Lx[r][bl][0];
            const float L = Ls.x, s = Ls.y;

            v2f ap = L * g_p;                     // v_pk_mul
            v2f an = L * g_n;
            v2f ep, en;
            ep.x = __builtin_amdgcn_exp2f(ap.x); ep.y = __builtin_amdgcn_exp2f(ap.y);
            en.x = __builtin_amdgcn_exp2f(an.x); en.y = __builtin_amdgcn_exp2f(an.y);

            v2f u = ep - en;                      // v_pk_add
            accB += s * u;                        // v_pk_fma (s broadcast)
            v2f v = w_p * u + w_d * en;           // pk_mul + pk_fma
            accA += s * v;
        }
    }

    // ---- write A/B partials (coalesced float2) ----
    {
        size_t base = (size_t)bz * (NB * N_OUT) + (b0 + bl) * N_OUT + j0 + tj2 * 2;
        *(float2*)&ws[AOFF + base] = make_float2(accA.x, accA.y);
        *(float2*)&ws[BOFF + base] = make_float2(accB.x, accB.y);
    }

    // ---- tile weight-max slot (one writer set: by==0; jx covers 16 j-tiles) ----
    if (by == 0) {
        __syncthreads();                 // all Lx reads done; safe to alias
        float* qred = &Lx[0][0][0];
        #pragma unroll
        for (int off = 32; off; off >>= 1) m_w = fmaxf(m_w, __shfl_xor(m_w, off));
        if ((tid & 63) == 0) qred[tid >> 6] = m_w;
        __syncthreads();
        if (tid == 0)
            ws[jx * Z + bz] = fmaxf(fmaxf(qred[0], qred[1]), fmaxf(qred[2], qred[3]));
    }
}

__global__ void reduce_combine(const float* __restrict__ ws,
                               const float* __restrict__ bp,
                               const float* __restrict__ bn,
                               const float* __restrict__ npar,
                               float* __restrict__ out) {
    __shared__ float qs[4];
    const int tid = threadIdx.x;

    // q = max(256 tile slots, bias weights) / 9
    float mm = ws[tid];                       // 256 slots over 256 threads
    float2 a2 = ((const float2*)bp)[tid];     // 512 floats over 256 threads
    float2 b2 = ((const float2*)bn)[tid];
    mm = fmaxf(mm, fmaxf(fmaxf(a2.x, a2.y), fmaxf(b2.x, b2.y)));
    #pragma unroll
    for (int off = 32; off; off >>= 1) mm = fmaxf(mm, __shfl_xor(mm, off));
    if ((tid & 63) == 0) qs[tid >> 6] = mm;
    __syncthreads();
    const float q = fmaxf(fmaxf(qs[0], qs[1]), fmaxf(qs[2], qs[3])) * (1.0f / 9.0f);

    const int g = blockIdx.x * 256 + tid;     // float4 index, 0..16383
    const float4* A4 = (const float4*)(ws + AOFF);
    const float4* B4 = (const float4*)(ws + BOFF);
    float ax = 0.f, ay = 0.f, az = 0.f, aw = 0.f;
    float bx = 0.f, byy = 0.f, bz2 = 0.f, bw = 0.f;
    #pragma unroll
    for (int z = 0; z < Z; ++z) {
        float4 va = A4[(size_t)z * (NB * N_OUT / 4) + g];
        float4 vb = B4[(size_t)z * (NB * N_OUT / 4) + g];
        ax += va.x; ay += va.y; az += va.z; aw += va.w;
        bx += vb.x; byy += vb.y; bz2 += vb.z; bw += vb.w;
    }
    const int j = (g * 4) & (N_OUT - 1);
    float4 bpv = *(const float4*)&bp[j];
    float4 bnv = *(const float4*)&bn[j];
    const float* nrow = &npar[N_IN * (2 * N_OUT) + 2 * j];
    float4 n0 = *(const float4*)&nrow[0];     // (np0,nn0,np1,nn1)
    float4 n1 = *(const float4*)&nrow[4];     // (np2,nn2,np3,nn3)
    float y0 = 0.5f * (ax + bpv.x * n0.x - bnv.x * n0.y + q * (bx  + n0.x - n0.y));
    float y1 = 0.5f * (ay + bpv.y * n0.z - bnv.y * n0.w + q * (byy + n0.z - n0.w));
    float y2 = 0.5f * (az + bpv.z * n1.x - bnv.z * n1.y + q * (bz2 + n1.x - n1.y));
    float y3 = 0.5f * (aw + bpv.w * n1.z - bnv.w * n1.w + q * (bw  + n1.z - n1.w));
    ((float4*)out)[g] = make_float4(y0, y1, y2, y3);
}

extern "C" void kernel_launch(void* const* d_in, const int* in_sizes, int n_in,
                              void* d_out, int out_size, void* d_ws, size_t ws_size,
                              hipStream_t stream) {
    const float* x    = (const float*)d_in[0];
    const float* wp   = (const float*)d_in[1];
    const float* wn   = (const float*)d_in[2];
    const float* bp   = (const float*)d_in[3];
    const float* bn   = (const float*)d_in[4];
    const float* npar = (const float*)d_in[5];
    float* out = (float*)d_out;
    float* ws  = (float*)d_ws;   // 256 slots + 8 MiB A/B partials

    dim3 grid(N_OUT / JT, NB / BT, Z);   // (16,8,16) = 2048 blocks, 8/CU
    memristor_mainAB<<<grid, 256, 0, stream>>>(x, wp, wn, npar, ws);

    reduce_combine<<<(NB * N_OUT / 4) / 256, 256, 0, stream>>>(ws, bp, bn, npar, out);
}

// Round 15
// 32.841 us; speedup vs baseline: 2.4103x; 1.1652x over previous
//
#include <hip/hip_runtime.h>

// Memristor dense fwd. q = max_w/9 enters linearly:
//   y[b,j] = 0.5*[ A + biasA + q*(B + biasB) ]
//   A = sum_r s*(wp*t^gp - wn*t^gn),  B = sum_r s*(t^gp - t^gn)
//   biasA = bp*n_pos - bn*n_neg, biasB = n_pos - n_neg  (bias row t=2 -> t^g = n)
// t = max(2|x|,1e-12), s = sign(x), L = log2(t), g = log2(n_param).
// Inner loop (wd = wp-wn staged): u = ep-en; B += s*u; A += s*(wp*u + wd*en).
// R15: main is LDS-BW-bound (9 B/exp2) -> 2b x 4j micro-tile cuts it to 5 B/exp2:
//   BT=32, grid (8,4,16)=512 blocks; weight redundancy 8->4. Else R10 verbatim.

#define N_IN 1024
#define N_OUT 512
#define NB 128
#define Z 16            // r-split across grid.z (64 rows per block)
#define RPC 32          // rows per staged chunk (2 chunks per block)
#define JT 64
#define BT 32

typedef float v2f __attribute__((ext_vector_type(2)));

// ws float layout: [0..127] tile-max slots (slot = jx*16+bz);
//   A partials at AOFF: [Z][NB][N_OUT] = 4 MiB; B partials at BOFF: 4 MiB.
#define AOFF 1024
#define BOFF (1024 + Z * NB * N_OUT)

__launch_bounds__(256, 4)
__global__ void memristor_mainAB(const float* __restrict__ x,
                                 const float* __restrict__ wp,
                                 const float* __restrict__ wn,
                                 const float* __restrict__ npar,
                                 float* __restrict__ ws) {
    // Wg[r][arr][grp][4]: arr 0=wp, 1=wd=wp-wn, 2=gp, 3=gn; grp XOR-swizzled by r
    __shared__ float Wg[RPC][4][16][4];   // 32 KiB
    __shared__ float Lx[RPC][BT][2];      // 8 KiB: (L, s), r-major

    const int tid = threadIdx.x;
    const int jx = blockIdx.x, by = blockIdx.y, bz = blockIdx.z;
    const int j0 = jx * JT;
    const int b0 = by * BT;

    const int tj4 = tid & 15;       // j group (4 cols)
    const int bl0 = (tid >> 4) * 2; // b pair

    v2f accA0_01 = {0.f,0.f}, accA0_23 = {0.f,0.f};
    v2f accA1_01 = {0.f,0.f}, accA1_23 = {0.f,0.f};
    v2f accB0_01 = {0.f,0.f}, accB0_23 = {0.f,0.f};
    v2f accB1_01 = {0.f,0.f}, accB1_23 = {0.f,0.f};
    float m_w = 0.0f;               // tile weight max (free: data already in regs)

    for (int c = 0; c < 2; ++c) {
        const int rbase = bz * 64 + c * RPC;
        __syncthreads();   // protect LDS reuse across chunks
        {   // stage x: 32 b x 32 r; lane-consecutive b for conflict-free LDS writes
            int bl = tid & 31;      // b row
            int rq = tid >> 5;      // 0..7: float4 along r
            float4 v = *(const float4*)&x[(b0 + bl) * N_IN + rbase + rq * 4];
            float vv[4] = {v.x, v.y, v.z, v.w};
            #pragma unroll
            for (int k = 0; k < 4; ++k) {
                float val = vv[k];
                float s = (val > 0.f) ? 1.f : ((val < 0.f) ? -1.f : 0.f);
                float t = fmaxf(2.f * fabsf(val), 1e-12f);
                Lx[rq * 4 + k][bl][0] = __builtin_amdgcn_logf(t);   // log2
                Lx[rq * 4 + k][bl][1] = s;
            }
        }
        {   // stage weights (wp, wd) + gammas: 32 r-rows x 64 j-cols; 8 j per thread
            int rr = tid >> 3;          // 0..31
            int cg = tid & 7;           // 0..7
            int pg0 = (2 * cg) ^ (rr & 15);
            int pg1 = (2 * cg + 1) ^ (rr & 15);
            {
                const float* prow = &wp[(rbase + rr) * N_OUT + j0 + cg * 8];
                const float* nrow = &wn[(rbase + rr) * N_OUT + j0 + cg * 8];
                float4 pa = *(const float4*)&prow[0];
                float4 pb = *(const float4*)&prow[4];
                float4 na = *(const float4*)&nrow[0];
                float4 nb = *(const float4*)&nrow[4];
                *(float4*)&Wg[rr][0][pg0][0] = pa;
                *(float4*)&Wg[rr][0][pg1][0] = pb;
                *(float4*)&Wg[rr][1][pg0][0] = make_float4(pa.x - na.x, pa.y - na.y,
                                                           pa.z - na.z, pa.w - na.w);
                *(float4*)&Wg[rr][1][pg1][0] = make_float4(pb.x - nb.x, pb.y - nb.y,
                                                           pb.z - nb.z, pb.w - nb.w);
                m_w = fmaxf(m_w, fmaxf(fmaxf(pa.x, pa.y), fmaxf(pa.z, pa.w)));
                m_w = fmaxf(m_w, fmaxf(fmaxf(pb.x, pb.y), fmaxf(pb.z, pb.w)));
                m_w = fmaxf(m_w, fmaxf(fmaxf(na.x, na.y), fmaxf(na.z, na.w)));
                m_w = fmaxf(m_w, fmaxf(fmaxf(nb.x, nb.y), fmaxf(nb.z, nb.w)));
            }
            {
                const float* grow = &npar[(rbase + rr) * (2 * N_OUT) + 2 * j0 + cg * 16];
                float4 f0 = *(const float4*)&grow[0];    // p0 n0 p1 n1
                float4 f1 = *(const float4*)&grow[4];    // p2 n2 p3 n3
                float4 f2 = *(const float4*)&grow[8];
                float4 f3 = *(const float4*)&grow[12];
                *(float4*)&Wg[rr][2][pg0][0] = make_float4(
                    __builtin_amdgcn_logf(f0.x), __builtin_amdgcn_logf(f0.z),
                    __builtin_amdgcn_logf(f1.x), __builtin_amdgcn_logf(f1.z));
                *(float4*)&Wg[rr][3][pg0][0] = make_float4(
                    __builtin_amdgcn_logf(f0.y), __builtin_amdgcn_logf(f0.w),
                    __builtin_amdgcn_logf(f1.y), __builtin_amdgcn_logf(f1.w));
                *(float4*)&Wg[rr][2][pg1][0] = make_float4(
                    __builtin_amdgcn_logf(f2.x), __builtin_amdgcn_logf(f2.z),
                    __builtin_amdgcn_logf(f3.x), __builtin_amdgcn_logf(f3.z));
                *(float4*)&Wg[rr][3][pg1][0] = make_float4(
                    __builtin_amdgcn_logf(f2.y), __builtin_amdgcn_logf(f2.w),
                    __builtin_amdgcn_logf(f3.y), __builtin_amdgcn_logf(f3.w));
            }
        }
        __syncthreads();

        #pragma unroll 4
        for (int r = 0; r < RPC; ++r) {
            const float4* wrow = (const float4*)&Wg[r][0][tj4 ^ (r & 15)][0];
            float4 w_p = wrow[0];
            float4 w_d = wrow[16];
            float4 g_p = wrow[32];
            float4 g_n = wrow[48];
            float4 l01 = *(const float4*)&Lx[r][bl0][0];   // (L0,s0,L1,s1)

            v2f wp01 = {w_p.x, w_p.y}, wp23 = {w_p.z, w_p.w};
            v2f wd01 = {w_d.x, w_d.y}, wd23 = {w_d.z, w_d.w};
            v2f gp01 = {g_p.x, g_p.y}, gp23 = {g_p.z, g_p.w};
            v2f gn01 = {g_n.x, g_n.y}, gn23 = {g_n.z, g_n.w};

            {   // b row 0
                const float L = l01.x, s = l01.y;
                v2f ap01 = L * gp01, ap23 = L * gp23;
                v2f an01 = L * gn01, an23 = L * gn23;
                v2f ep01, ep23, en01, en23;
                ep01.x = __builtin_amdgcn_exp2f(ap01.x); ep01.y = __builtin_amdgcn_exp2f(ap01.y);
                ep23.x = __builtin_amdgcn_exp2f(ap23.x); ep23.y = __builtin_amdgcn_exp2f(ap23.y);
                en01.x = __builtin_amdgcn_exp2f(an01.x); en01.y = __builtin_amdgcn_exp2f(an01.y);
                en23.x = __builtin_amdgcn_exp2f(an23.x); en23.y = __builtin_amdgcn_exp2f(an23.y);
                v2f u01 = ep01 - en01, u23 = ep23 - en23;
                accB0_01 += s * u01;
                accB0_23 += s * u23;
                v2f v01 = wp01 * u01 + wd01 * en01;
                v2f v23 = wp23 * u23 + wd23 * en23;
                accA0_01 += s * v01;
                accA0_23 += s * v23;
            }
            {   // b row 1
                const float L = l01.z, s = l01.w;
                v2f ap01 = L * gp01, ap23 = L * gp23;
                v2f an01 = L * gn01, an23 = L * gn23;
                v2f ep01, ep23, en01, en23;
                ep01.x = __builtin_amdgcn_exp2f(ap01.x); ep01.y = __builtin_amdgcn_exp2f(ap01.y);
                ep23.x = __builtin_amdgcn_exp2f(ap23.x); ep23.y = __builtin_amdgcn_exp2f(ap23.y);
                en01.x = __builtin_amdgcn_exp2f(an01.x); en01.y = __builtin_amdgcn_exp2f(an01.y);
                en23.x = __builtin_amdgcn_exp2f(an23.x); en23.y = __builtin_amdgcn_exp2f(an23.y);
                v2f u01 = ep01 - en01, u23 = ep23 - en23;
                accB1_01 += s * u01;
                accB1_23 += s * u23;
                v2f v01 = wp01 * u01 + wd01 * en01;
                v2f v23 = wp23 * u23 + wd23 * en23;
                accA1_01 += s * v01;
                accA1_23 += s * v23;
            }
        }
    }

    // ---- write A/B partials (coalesced float4, 2 b rows) ----
    {
        size_t base = (size_t)bz * (NB * N_OUT) + (b0 + bl0) * N_OUT + j0 + tj4 * 4;
        *(float4*)&ws[AOFF + base]         = make_float4(accA0_01.x, accA0_01.y, accA0_23.x, accA0_23.y);
        *(float4*)&ws[AOFF + base + N_OUT] = make_float4(accA1_01.x, accA1_01.y, accA1_23.x, accA1_23.y);
        *(float4*)&ws[BOFF + base]         = make_float4(accB0_01.x, accB0_01.y, accB0_23.x, accB0_23.y);
        *(float4*)&ws[BOFF + base + N_OUT] = make_float4(accB1_01.x, accB1_01.y, accB1_23.x, accB1_23.y);
    }

    // ---- tile weight-max slot (one writer set: by==0) ----
    if (by == 0) {
        __syncthreads();                 // all Lx reads done; safe to alias
        float* qred = &Lx[0][0][0];
        #pragma unroll
        for (int off = 32; off; off >>= 1) m_w = fmaxf(m_w, __shfl_xor(m_w, off));
        if ((tid & 63) == 0) qred[tid >> 6] = m_w;
        __syncthreads();
        if (tid == 0)
            ws[jx * Z + bz] = fmaxf(fmaxf(qred[0], qred[1]), fmaxf(qred[2], qred[3]));
    }
}

__global__ void reduce_combine(const float* __restrict__ ws,
                               const float* __restrict__ bp,
                               const float* __restrict__ bn,
                               const float* __restrict__ npar,
                               float* __restrict__ out) {
    __shared__ float qs[4];
    const int tid = threadIdx.x;

    // q = max(128 tile slots, bias weights) / 9
    float mm = (tid < 128) ? ws[tid] : 0.0f;
    float2 a2 = ((const float2*)bp)[tid];     // 512 floats over 256 threads
    float2 b2 = ((const float2*)bn)[tid];
    mm = fmaxf(mm, fmaxf(fmaxf(a2.x, a2.y), fmaxf(b2.x, b2.y)));
    #pragma unroll
    for (int off = 32; off; off >>= 1) mm = fmaxf(mm, __shfl_xor(mm, off));
    if ((tid & 63) == 0) qs[tid >> 6] = mm;
    __syncthreads();
    const float q = fmaxf(fmaxf(qs[0], qs[1]), fmaxf(qs[2], qs[3])) * (1.0f / 9.0f);

    const int g = blockIdx.x * 256 + tid;     // float4 index, 0..16383
    const float4* A4 = (const float4*)(ws + AOFF);
    const float4* B4 = (const float4*)(ws + BOFF);
    float ax = 0.f, ay = 0.f, az = 0.f, aw = 0.f;
    float bx = 0.f, byy = 0.f, bz2 = 0.f, bw = 0.f;
    #pragma unroll
    for (int z = 0; z < Z; ++z) {
        float4 va = A4[(size_t)z * (NB * N_OUT / 4) + g];
        float4 vb = B4[(size_t)z * (NB * N_OUT / 4) + g];
        ax += va.x; ay += va.y; az += va.z; aw += va.w;
        bx += vb.x; byy += vb.y; bz2 += vb.z; bw += vb.w;
    }
    const int j = (g * 4) & (N_OUT - 1);
    float4 bpv = *(const float4*)&bp[j];
    float4 bnv = *(const float4*)&bn[j];
    const float* nrow = &npar[N_IN * (2 * N_OUT) + 2 * j];
    float4 n0 = *(const float4*)&nrow[0];     // (np0,nn0,np1,nn1)
    float4 n1 = *(const float4*)&nrow[4];     // (np2,nn2,np3,nn3)
    float y0 = 0.5f * (ax + bpv.x * n0.x - bnv.x * n0.y + q * (bx  + n0.x - n0.y));
    float y1 = 0.5f * (ay + bpv.y * n0.z - bnv.y * n0.w + q * (byy + n0.z - n0.w));
    float y2 = 0.5f * (az + bpv.z * n1.x - bnv.z * n1.y + q * (bz2 + n1.x - n1.y));
    float y3 = 0.5f * (aw + bpv.w * n1.z - bnv.w * n1.w + q * (bw  + n1.z - n1.w));
    ((float4*)out)[g] = make_float4(y0, y1, y2, y3);
}

extern "C" void kernel_launch(void* const* d_in, const int* in_sizes, int n_in,
                              void* d_out, int out_size, void* d_ws, size_t ws_size,
                              hipStream_t stream) {
    const float* x    = (const float*)d_in[0];
    const float* wp   = (const float*)d_in[1];
    const float* wn   = (const float*)d_in[2];
    const float* bp   = (const float*)d_in[3];
    const float* bn   = (const float*)d_in[4];
    const float* npar = (const float*)d_in[5];
    float* out = (float*)d_out;
    float* ws  = (float*)d_ws;   // 128 slots + 8 MiB A/B partials

    dim3 grid(N_OUT / JT, NB / BT, Z);   // (8,4,16) = 512 blocks, 2/CU
    memristor_mainAB<<<grid, 256, 0, stream>>>(x, wp, wn, npar, ws);

    reduce_combine<<<(NB * N_OUT / 4) / 256, 256, 0, stream>>>(ws, bp, bn, npar, out);
}

// Round 16
// 30.272 us; speedup vs baseline: 2.6148x; 1.0848x over previous
//
#include <hip/hip_runtime.h>

// Memristor dense fwd. q = max_w/9 enters linearly:
//   y[b,j] = 0.5*[ A + biasA + q*(B + biasB) ]
//   A = sum_r s*(wp*t^gp - wn*t^gn),  B = sum_r s*(t^gp - t^gn)
//   biasA = bp*n_pos - bn*n_neg, biasB = n_pos - n_neg  (bias row t=2 -> t^g = n)
// t = max(2|x|,1e-12), s = sign(x), L = log2(t), g = log2(n_param).
// Inner loop (wd = wp-wn staged): u = ep-en; B += s*u; A += s*(wp*u + wd*en).
// R16: issue-bound main -> cut non-trans overhead: 4b x 4j micro-tile (BT=64,
// redundancy 4->2, 3 B LDS/exp2), f16 partials (half partial traffic),
// reduce re-gridded to 256 blocks x 64 thr (BW-saturating, single-wave q).

#define N_IN 1024
#define N_OUT 512
#define NB 128
#define Z 16            // r-split across grid.z (64 rows per block)
#define RPC 32          // rows per staged chunk (2 chunks per block)
#define JT 64
#define BT 64

typedef float v2f __attribute__((ext_vector_type(2)));
typedef _Float16 h4 __attribute__((ext_vector_type(4)));

// ws layout: float[0..127] tile-max slots (slot = jx*16+bz);
//   A partials (half) at ws+1024: [Z][NB][N_OUT] halfs = 2 MiB;
//   B partials (half) right after: 2 MiB.
#define PLEN (Z * NB * N_OUT)   // halfs per array

__launch_bounds__(256, 2)
__global__ void memristor_mainAB(const float* __restrict__ x,
                                 const float* __restrict__ wp,
                                 const float* __restrict__ wn,
                                 const float* __restrict__ npar,
                                 float* __restrict__ ws) {
    // Wg[r][arr][grp][4]: arr 0=wp, 1=wd=wp-wn, 2=gp, 3=gn; grp XOR-swizzled by r
    __shared__ float Wg[RPC][4][16][4];   // 32 KiB
    __shared__ float Lx[RPC][BT][2];      // 16 KiB: (L, s), r-major

    const int tid = threadIdx.x;
    const int jx = blockIdx.x, by = blockIdx.y, bz = blockIdx.z;
    const int j0 = jx * JT;
    const int b0 = by * BT;

    const int tj4 = tid & 15;       // j group (4 cols)
    const int bl0 = (tid >> 4) * 4; // 4 b rows per thread

    v2f accA[4][2];                 // [brow][jpair]
    v2f accB[4][2];
    #pragma unroll
    for (int i = 0; i < 4; ++i) {
        accA[i][0] = (v2f){0.f, 0.f}; accA[i][1] = (v2f){0.f, 0.f};
        accB[i][0] = (v2f){0.f, 0.f}; accB[i][1] = (v2f){0.f, 0.f};
    }
    float m_w = 0.0f;               // tile weight max (free: data already in regs)

    for (int c = 0; c < 2; ++c) {
        const int rbase = bz * 64 + c * RPC;
        __syncthreads();   // protect LDS reuse across chunks
        {   // stage x: 64 b x 32 r; 8 r per thread (2 float4)
            int bl = tid & 63;      // b row
            int rq = tid >> 6;      // 0..3
            float4 v0 = *(const float4*)&x[(b0 + bl) * N_IN + rbase + rq * 8];
            float4 v1 = *(const float4*)&x[(b0 + bl) * N_IN + rbase + rq * 8 + 4];
            float vv[8] = {v0.x, v0.y, v0.z, v0.w, v1.x, v1.y, v1.z, v1.w};
            #pragma unroll
            for (int k = 0; k < 8; ++k) {
                float val = vv[k];
                float s = (val > 0.f) ? 1.f : ((val < 0.f) ? -1.f : 0.f);
                float t = fmaxf(2.f * fabsf(val), 1e-12f);
                Lx[rq * 8 + k][bl][0] = __builtin_amdgcn_logf(t);   // log2
                Lx[rq * 8 + k][bl][1] = s;
            }
        }
        {   // stage weights (wp, wd) + gammas: 32 r-rows x 64 j-cols; 8 j per thread
            int rr = tid >> 3;          // 0..31
            int cg = tid & 7;           // 0..7
            int pg0 = (2 * cg) ^ (rr & 15);
            int pg1 = (2 * cg + 1) ^ (rr & 15);
            {
                const float* prow = &wp[(rbase + rr) * N_OUT + j0 + cg * 8];
                const float* nrow = &wn[(rbase + rr) * N_OUT + j0 + cg * 8];
                float4 pa = *(const float4*)&prow[0];
                float4 pb = *(const float4*)&prow[4];
                float4 na = *(const float4*)&nrow[0];
                float4 nb = *(const float4*)&nrow[4];
                *(float4*)&Wg[rr][0][pg0][0] = pa;
                *(float4*)&Wg[rr][0][pg1][0] = pb;
                *(float4*)&Wg[rr][1][pg0][0] = make_float4(pa.x - na.x, pa.y - na.y,
                                                           pa.z - na.z, pa.w - na.w);
                *(float4*)&Wg[rr][1][pg1][0] = make_float4(pb.x - nb.x, pb.y - nb.y,
                                                           pb.z - nb.z, pb.w - nb.w);
                m_w = fmaxf(m_w, fmaxf(fmaxf(pa.x, pa.y), fmaxf(pa.z, pa.w)));
                m_w = fmaxf(m_w, fmaxf(fmaxf(pb.x, pb.y), fmaxf(pb.z, pb.w)));
                m_w = fmaxf(m_w, fmaxf(fmaxf(na.x, na.y), fmaxf(na.z, na.w)));
                m_w = fmaxf(m_w, fmaxf(fmaxf(nb.x, nb.y), fmaxf(nb.z, nb.w)));
            }
            {
                const float* grow = &npar[(rbase + rr) * (2 * N_OUT) + 2 * j0 + cg * 16];
                float4 f0 = *(const float4*)&grow[0];    // p0 n0 p1 n1
                float4 f1 = *(const float4*)&grow[4];    // p2 n2 p3 n3
                float4 f2 = *(const float4*)&grow[8];
                float4 f3 = *(const float4*)&grow[12];
                *(float4*)&Wg[rr][2][pg0][0] = make_float4(
                    __builtin_amdgcn_logf(f0.x), __builtin_amdgcn_logf(f0.z),
                    __builtin_amdgcn_logf(f1.x), __builtin_amdgcn_logf(f1.z));
                *(float4*)&Wg[rr][3][pg0][0] = make_float4(
                    __builtin_amdgcn_logf(f0.y), __builtin_amdgcn_logf(f0.w),
                    __builtin_amdgcn_logf(f1.y), __builtin_amdgcn_logf(f1.w));
                *(float4*)&Wg[rr][2][pg1][0] = make_float4(
                    __builtin_amdgcn_logf(f2.x), __builtin_amdgcn_logf(f2.z),
                    __builtin_amdgcn_logf(f3.x), __builtin_amdgcn_logf(f3.z));
                *(float4*)&Wg[rr][3][pg1][0] = make_float4(
                    __builtin_amdgcn_logf(f2.y), __builtin_amdgcn_logf(f2.w),
                    __builtin_amdgcn_logf(f3.y), __builtin_amdgcn_logf(f3.w));
            }
        }
        __syncthreads();

        #pragma unroll 4
        for (int r = 0; r < RPC; ++r) {
            const float4* wrow = (const float4*)&Wg[r][0][tj4 ^ (r & 15)][0];
            float4 w_p = wrow[0];
            float4 w_d = wrow[16];
            float4 g_p = wrow[32];
            float4 g_n = wrow[48];
            float4 l01 = *(const float4*)&Lx[r][bl0][0];       // (L0,s0,L1,s1)
            float4 l23 = *(const float4*)&Lx[r][bl0 + 2][0];   // (L2,s2,L3,s3)

            v2f wp01 = {w_p.x, w_p.y}, wp23 = {w_p.z, w_p.w};
            v2f wd01 = {w_d.x, w_d.y}, wd23 = {w_d.z, w_d.w};
            v2f gp01 = {g_p.x, g_p.y}, gp23 = {g_p.z, g_p.w};
            v2f gn01 = {g_n.x, g_n.y}, gn23 = {g_n.z, g_n.w};
            float Lv[4] = {l01.x, l01.z, l23.x, l23.z};
            float Sv[4] = {l01.y, l01.w, l23.y, l23.w};

            #pragma unroll
            for (int ib = 0; ib < 4; ++ib) {
                const float L = Lv[ib], s = Sv[ib];
                v2f ap01 = L * gp01, ap23 = L * gp23;
                v2f an01 = L * gn01, an23 = L * gn23;
                v2f ep01, ep23, en01, en23;
                ep01.x = __builtin_amdgcn_exp2f(ap01.x); ep01.y = __builtin_amdgcn_exp2f(ap01.y);
                ep23.x = __builtin_amdgcn_exp2f(ap23.x); ep23.y = __builtin_amdgcn_exp2f(ap23.y);
                en01.x = __builtin_amdgcn_exp2f(an01.x); en01.y = __builtin_amdgcn_exp2f(an01.y);
                en23.x = __builtin_amdgcn_exp2f(an23.x); en23.y = __builtin_amdgcn_exp2f(an23.y);
                v2f u01 = ep01 - en01, u23 = ep23 - en23;
                accB[ib][0] += s * u01;
                accB[ib][1] += s * u23;
                v2f v01 = wp01 * u01 + wd01 * en01;
                v2f v23 = wp23 * u23 + wd23 * en23;
                accA[ib][0] += s * v01;
                accA[ib][1] += s * v23;
            }
        }
    }

    // ---- write A/B partials as f16 (8B per brow per array, coalesced) ----
    {
        _Float16* hA = (_Float16*)(ws + 1024);
        _Float16* hB = hA + PLEN;
        size_t base = (size_t)bz * (NB * N_OUT) + (b0 + bl0) * N_OUT + j0 + tj4 * 4;
        #pragma unroll
        for (int ib = 0; ib < 4; ++ib) {
            h4 ha = {(_Float16)accA[ib][0].x, (_Float16)accA[ib][0].y,
                     (_Float16)accA[ib][1].x, (_Float16)accA[ib][1].y};
            h4 hb = {(_Float16)accB[ib][0].x, (_Float16)accB[ib][0].y,
                     (_Float16)accB[ib][1].x, (_Float16)accB[ib][1].y};
            *(h4*)&hA[base + (size_t)ib * N_OUT] = ha;
            *(h4*)&hB[base + (size_t)ib * N_OUT] = hb;
        }
    }

    // ---- tile weight-max slot (one writer set: by==0) ----
    if (by == 0) {
        __syncthreads();                 // all Lx reads done; safe to alias
        float* qred = &Lx[0][0][0];
        #pragma unroll
        for (int off = 32; off; off >>= 1) m_w = fmaxf(m_w, __shfl_xor(m_w, off));
        if ((tid & 63) == 0) qred[tid >> 6] = m_w;
        __syncthreads();
        if (tid == 0)
            ws[jx * Z + bz] = fmaxf(fmaxf(qred[0], qred[1]), fmaxf(qred[2], qred[3]));
    }
}

__global__ void reduce_combine(const float* __restrict__ ws,
                               const float* __restrict__ bp,
                               const float* __restrict__ bn,
                               const float* __restrict__ npar,
                               float* __restrict__ out) {
    const int tid = threadIdx.x;          // 64 threads (1 wave)
    const int g = blockIdx.x * 64 + tid;  // float4-of-output index, 0..16383

    // q = max(128 tile slots, bias weights) / 9 — single-wave reduce
    float mm = fmaxf(ws[tid], ws[tid + 64]);
    {
        const float4* b4 = (const float4*)&bp[tid * 8];
        const float4* c4 = (const float4*)&bn[tid * 8];
        float4 p0 = b4[0], p1 = b4[1], q0 = c4[0], q1 = c4[1];
        mm = fmaxf(mm, fmaxf(fmaxf(p0.x, p0.y), fmaxf(p0.z, p0.w)));
        mm = fmaxf(mm, fmaxf(fmaxf(p1.x, p1.y), fmaxf(p1.z, p1.w)));
        mm = fmaxf(mm, fmaxf(fmaxf(q0.x, q0.y), fmaxf(q0.z, q0.w)));
        mm = fmaxf(mm, fmaxf(fmaxf(q1.x, q1.y), fmaxf(q1.z, q1.w)));
    }
    #pragma unroll
    for (int off = 32; off; off >>= 1) mm = fmaxf(mm, __shfl_xor(mm, off));
    const float q = mm * (1.0f / 9.0f);

    const h4* hA = (const h4*)((const _Float16*)(ws + 1024));
    const h4* hB = hA + PLEN / 4;
    float ax = 0.f, ay = 0.f, az = 0.f, aw = 0.f;
    float bx = 0.f, byy = 0.f, bz2 = 0.f, bw = 0.f;
    #pragma unroll
    for (int z = 0; z < Z; ++z) {
        h4 va = hA[(size_t)z * (NB * N_OUT / 4) + g];
        h4 vb = hB[(size_t)z * (NB * N_OUT / 4) + g];
        ax += (float)va.x; ay += (float)va.y; az += (float)va.z; aw += (float)va.w;
        bx += (float)vb.x; byy += (float)vb.y; bz2 += (float)vb.z; bw += (float)vb.w;
    }
    const int j = (g * 4) & (N_OUT - 1);
    float4 bpv = *(const float4*)&bp[j];
    float4 bnv = *(const float4*)&bn[j];
    const float* nrow = &npar[N_IN * (2 * N_OUT) + 2 * j];
    float4 n0 = *(const float4*)&nrow[0];     // (np0,nn0,np1,nn1)
    float4 n1 = *(const float4*)&nrow[4];     // (np2,nn2,np3,nn3)
    float y0 = 0.5f * (ax + bpv.x * n0.x - bnv.x * n0.y + q * (bx  + n0.x - n0.y));
    float y1 = 0.5f * (ay + bpv.y * n0.z - bnv.y * n0.w + q * (byy + n0.z - n0.w));
    float y2 = 0.5f * (az + bpv.z * n1.x - bnv.z * n1.y + q * (bz2 + n1.x - n1.y));
    float y3 = 0.5f * (aw + bpv.w * n1.z - bnv.w * n1.w + q * (bw  + n1.z - n1.w));
    ((float4*)out)[g] = make_float4(y0, y1, y2, y3);
}

extern "C" void kernel_launch(void* const* d_in, const int* in_sizes, int n_in,
                              void* d_out, int out_size, void* d_ws, size_t ws_size,
                              hipStream_t stream) {
    const float* x    = (const float*)d_in[0];
    const float* wp   = (const float*)d_in[1];
    const float* wn   = (const float*)d_in[2];
    const float* bp   = (const float*)d_in[3];
    const float* bn   = (const float*)d_in[4];
    const float* npar = (const float*)d_in[5];
    float* out = (float*)d_out;
    float* ws  = (float*)d_ws;   // 128 slots + 4 MiB f16 A/B partials

    dim3 grid(N_OUT / JT, NB / BT, Z);   // (8,2,16) = 256 blocks, 1/CU
    memristor_mainAB<<<grid, 256, 0, stream>>>(x, wp, wn, npar, ws);

    reduce_combine<<<(NB * N_OUT / 4) / 64, 64, 0, stream>>>(ws, bp, bn, npar, out);
}

// Round 17
// 30.248 us; speedup vs baseline: 2.6169x; 1.0008x over previous
//
#include <hip/hip_runtime.h>

// Memristor dense fwd. q = max_w/9 enters linearly:
//   y[b,j] = 0.5*[ A + biasA + q*(B + biasB) ]
//   A = sum_r s*(wp*t^gp - wn*t^gn),  B = sum_r s*(t^gp - t^gn)
//   biasA = bp*n_pos - bn*n_neg, biasB = n_pos - n_neg  (bias row t=2 -> t^g = n)
// t = max(2|x|,1e-12), s = sign(x), L = log2(t), g = log2(n_param).
// Inner loop (wd = wp-wn staged): u = ep-en; B += s*u; A += s*(wp*u + wd*en).
// R17: R16 was 1 wave/SIMD (trans+VALU serialized). JT 64->32 at BT=64:
//   grid (16,2,16)=512 blocks = 2/CU = 2 waves/SIMD -> VALU/LDS hide under
//   trans shadow; redundancy & partial volume unchanged; 4b x 2j per thread.

#define N_IN 1024
#define N_OUT 512
#define NB 128
#define Z 16            // r-split across grid.z (64 rows per block)
#define RPC 32          // rows per staged chunk (2 chunks per block)
#define JT 32
#define BT 64

typedef float v2f __attribute__((ext_vector_type(2)));
typedef _Float16 h2 __attribute__((ext_vector_type(2)));
typedef _Float16 h4 __attribute__((ext_vector_type(4)));

// ws layout: float[0..255] tile-max slots (slot = jx*16+bz);
//   A partials (half) at ws+1024: [Z][NB][N_OUT] halfs = 2 MiB; B right after.
#define PLEN (Z * NB * N_OUT)   // halfs per array

__launch_bounds__(256, 2)
__global__ void memristor_mainAB(const float* __restrict__ x,
                                 const float* __restrict__ wp,
                                 const float* __restrict__ wn,
                                 const float* __restrict__ npar,
                                 float* __restrict__ ws) {
    // Wg[r][arr][grp][4]: arr 0=wp, 1=wd=wp-wn, 2=gp, 3=gn; grp XOR-swizzled by r&7
    __shared__ float Wg[RPC][4][8][4];    // 16 KiB
    __shared__ float Lx[RPC][BT][2];      // 16 KiB: (L, s), r-major

    const int tid = threadIdx.x;
    const int jx = blockIdx.x, by = blockIdx.y, bz = blockIdx.z;
    const int j0 = jx * JT;
    const int b0 = by * BT;

    const int tj2 = tid & 15;       // j pair: j = j0 + tj2*2 (+0/1)
    const int bl0 = (tid >> 4) * 4; // 4 b rows per thread
    const int g8  = tj2 >> 1;       // Wg group
    const int sub = (tj2 & 1) * 2;  // float2 within group

    v2f accA[4], accB[4];
    #pragma unroll
    for (int i = 0; i < 4; ++i) { accA[i] = (v2f){0.f, 0.f}; accB[i] = (v2f){0.f, 0.f}; }
    float m_w = 0.0f;               // tile weight max (free: data already in regs)

    for (int c = 0; c < 2; ++c) {
        const int rbase = bz * 64 + c * RPC;
        __syncthreads();   // protect LDS reuse across chunks
        {   // stage x: 64 b x 32 r; 8 r per thread (2 float4)
            int bl = tid & 63;      // b row
            int rq = tid >> 6;      // 0..3
            float4 v0 = *(const float4*)&x[(b0 + bl) * N_IN + rbase + rq * 8];
            float4 v1 = *(const float4*)&x[(b0 + bl) * N_IN + rbase + rq * 8 + 4];
            float vv[8] = {v0.x, v0.y, v0.z, v0.w, v1.x, v1.y, v1.z, v1.w};
            #pragma unroll
            for (int k = 0; k < 8; ++k) {
                float val = vv[k];
                float s = (val > 0.f) ? 1.f : ((val < 0.f) ? -1.f : 0.f);
                float t = fmaxf(2.f * fabsf(val), 1e-12f);
                Lx[rq * 8 + k][bl][0] = __builtin_amdgcn_logf(t);   // log2
                Lx[rq * 8 + k][bl][1] = s;
            }
        }
        {   // stage weights (wp, wd) + gammas: 32 r-rows x 32 j-cols; 4 j per thread
            int rr = tid >> 3;          // 0..31
            int cg = tid & 7;           // 0..7
            int pg = cg ^ (rr & 7);     // XOR swizzle
            {
                const float* prow = &wp[(rbase + rr) * N_OUT + j0 + cg * 4];
                const float* nrow = &wn[(rbase + rr) * N_OUT + j0 + cg * 4];
                float4 pa = *(const float4*)&prow[0];
                float4 na = *(const float4*)&nrow[0];
                *(float4*)&Wg[rr][0][pg][0] = pa;
                *(float4*)&Wg[rr][1][pg][0] = make_float4(pa.x - na.x, pa.y - na.y,
                                                          pa.z - na.z, pa.w - na.w);
                m_w = fmaxf(m_w, fmaxf(fmaxf(pa.x, pa.y), fmaxf(pa.z, pa.w)));
                m_w = fmaxf(m_w, fmaxf(fmaxf(na.x, na.y), fmaxf(na.z, na.w)));
            }
            {
                const float* grow = &npar[(rbase + rr) * (2 * N_OUT) + 2 * j0 + cg * 8];
                float4 f0 = *(const float4*)&grow[0];    // p0 n0 p1 n1
                float4 f1 = *(const float4*)&grow[4];    // p2 n2 p3 n3
                *(float4*)&Wg[rr][2][pg][0] = make_float4(
                    __builtin_amdgcn_logf(f0.x), __builtin_amdgcn_logf(f0.z),
                    __builtin_amdgcn_logf(f1.x), __builtin_amdgcn_logf(f1.z));
                *(float4*)&Wg[rr][3][pg][0] = make_float4(
                    __builtin_amdgcn_logf(f0.y), __builtin_amdgcn_logf(f0.w),
                    __builtin_amdgcn_logf(f1.y), __builtin_amdgcn_logf(f1.w));
            }
        }
        __syncthreads();

        #pragma unroll 8
        for (int r = 0; r < RPC; ++r) {
            const float* wbase = &Wg[r][0][g8 ^ (r & 7)][sub];
            v2f w_p = *(const v2f*)&wbase[0];
            v2f w_d = *(const v2f*)&wbase[32];    // arr stride = 8 grp * 4 = 32 floats
            v2f g_p = *(const v2f*)&wbase[64];
            v2f g_n = *(const v2f*)&wbase[96];
            float4 l01 = *(const float4*)&Lx[r][bl0][0];       // (L0,s0,L1,s1)
            float4 l23 = *(const float4*)&Lx[r][bl0 + 2][0];   // (L2,s2,L3,s3)
            float Lv[4] = {l01.x, l01.z, l23.x, l23.z};
            float Sv[4] = {l01.y, l01.w, l23.y, l23.w};

            #pragma unroll
            for (int ib = 0; ib < 4; ++ib) {
                const float L = Lv[ib], s = Sv[ib];
                v2f ap = L * g_p;                 // v_pk_mul
                v2f an = L * g_n;
                v2f ep, en;
                ep.x = __builtin_amdgcn_exp2f(ap.x); ep.y = __builtin_amdgcn_exp2f(ap.y);
                en.x = __builtin_amdgcn_exp2f(an.x); en.y = __builtin_amdgcn_exp2f(an.y);
                v2f u = ep - en;                  // v_pk_add
                accB[ib] += s * u;                // v_pk_fma
                v2f v = w_p * u + w_d * en;       // pk_mul + pk_fma
                accA[ib] += s * v;
            }
        }
    }

    // ---- write A/B partials as f16 (h2 per brow per array) ----
    {
        _Float16* hA = (_Float16*)(ws + 1024);
        _Float16* hB = hA + PLEN;
        size_t base = (size_t)bz * (NB * N_OUT) + (b0 + bl0) * N_OUT + j0 + tj2 * 2;
        #pragma unroll
        for (int ib = 0; ib < 4; ++ib) {
            h2 ha = {(_Float16)accA[ib].x, (_Float16)accA[ib].y};
            h2 hb = {(_Float16)accB[ib].x, (_Float16)accB[ib].y};
            *(h2*)&hA[base + (size_t)ib * N_OUT] = ha;
            *(h2*)&hB[base + (size_t)ib * N_OUT] = hb;
        }
    }

    // ---- tile weight-max slot (one writer set: by==0) ----
    if (by == 0) {
        __syncthreads();                 // all Lx reads done; safe to alias
        float* qred = &Lx[0][0][0];
        #pragma unroll
        for (int off = 32; off; off >>= 1) m_w = fmaxf(m_w, __shfl_xor(m_w, off));
        if ((tid & 63) == 0) qred[tid >> 6] = m_w;
        __syncthreads();
        if (tid == 0)
            ws[jx * Z + bz] = fmaxf(fmaxf(qred[0], qred[1]), fmaxf(qred[2], qred[3]));
    }
}

__global__ void reduce_combine(const float* __restrict__ ws,
                               const float* __restrict__ bp,
                               const float* __restrict__ bn,
                               const float* __restrict__ npar,
                               float* __restrict__ out) {
    const int tid = threadIdx.x;          // 64 threads (1 wave)
    const int g = blockIdx.x * 64 + tid;  // float4-of-output index, 0..16383

    // q = max(256 tile slots, bias weights) / 9 — single-wave reduce
    float mm = fmaxf(fmaxf(ws[tid], ws[tid + 64]),
                     fmaxf(ws[tid + 128], ws[tid + 192]));
    {
        const float4* b4 = (const float4*)&bp[tid * 8];
        const float4* c4 = (const float4*)&bn[tid * 8];
        float4 p0 = b4[0], p1 = b4[1], q0 = c4[0], q1 = c4[1];
        mm = fmaxf(mm, fmaxf(fmaxf(p0.x, p0.y), fmaxf(p0.z, p0.w)));
        mm = fmaxf(mm, fmaxf(fmaxf(p1.x, p1.y), fmaxf(p1.z, p1.w)));
        mm = fmaxf(mm, fmaxf(fmaxf(q0.x, q0.y), fmaxf(q0.z, q0.w)));
        mm = fmaxf(mm, fmaxf(fmaxf(q1.x, q1.y), fmaxf(q1.z, q1.w)));
    }
    #pragma unroll
    for (int off = 32; off; off >>= 1) mm = fmaxf(mm, __shfl_xor(mm, off));
    const float q = mm * (1.0f / 9.0f);

    const h4* hA = (const h4*)((const _Float16*)(ws + 1024));
    const h4* hB = hA + PLEN / 4;
    float ax = 0.f, ay = 0.f, az = 0.f, aw = 0.f;
    float bx = 0.f, byy = 0.f, bz2 = 0.f, bw = 0.f;
    #pragma unroll
    for (int z = 0; z < Z; ++z) {
        h4 va = hA[(size_t)z * (NB * N_OUT / 4) + g];
        h4 vb = hB[(size_t)z * (NB * N_OUT / 4) + g];
        ax += (float)va.x; ay += (float)va.y; az += (float)va.z; aw += (float)va.w;
        bx += (float)vb.x; byy += (float)vb.y; bz2 += (float)vb.z; bw += (float)vb.w;
    }
    const int j = (g * 4) & (N_OUT - 1);
    float4 bpv = *(const float4*)&bp[j];
    float4 bnv = *(const float4*)&bn[j];
    const float* nrow = &npar[N_IN * (2 * N_OUT) + 2 * j];
    float4 n0 = *(const float4*)&nrow[0];     // (np0,nn0,np1,nn1)
    float4 n1 = *(const float4*)&nrow[4];     // (np2,nn2,np3,nn3)
    float y0 = 0.5f * (ax + bpv.x * n0.x - bnv.x * n0.y + q * (bx  + n0.x - n0.y));
    float y1 = 0.5f * (ay + bpv.y * n0.z - bnv.y * n0.w + q * (byy + n0.z - n0.w));
    float y2 = 0.5f * (az + bpv.z * n1.x - bnv.z * n1.y + q * (bz2 + n1.x - n1.y));
    float y3 = 0.5f * (aw + bpv.w * n1.z - bnv.w * n1.w + q * (bw  + n1.z - n1.w));
    ((float4*)out)[g] = make_float4(y0, y1, y2, y3);
}

extern "C" void kernel_launch(void* const* d_in, const int* in_sizes, int n_in,
                              void* d_out, int out_size, void* d_ws, size_t ws_size,
                              hipStream_t stream) {
    const float* x    = (const float*)d_in[0];
    const float* wp   = (const float*)d_in[1];
    const float* wn   = (const float*)d_in[2];
    const float* bp   = (const float*)d_in[3];
    const float* bn   = (const float*)d_in[4];
    const float* npar = (const float*)d_in[5];
    float* out = (float*)d_out;
    float* ws  = (float*)d_ws;   // 256 slots + 4 MiB f16 A/B partials

    dim3 grid(N_OUT / JT, NB / BT, Z);   // (16,2,16) = 512 blocks, 2/CU
    memristor_mainAB<<<grid, 256, 0, stream>>>(x, wp, wn, npar, ws);

    reduce_combine<<<(NB * N_OUT / 4) / 64, 64, 0, stream>>>(ws, bp, bn, npar, out);
}

// Round 18
// 29.353 us; speedup vs baseline: 2.6967x; 1.0305x over previous
//
#include <hip/hip_runtime.h>

// Memristor dense fwd. q = max_w/9 enters linearly:
//   y[b,j] = 0.5*[ A + biasA + q*(B + biasB) ]
//   A = sum_r s*(wp*t^gp - wn*t^gn),  B = sum_r s*(t^gp - t^gn)
//   biasA = bp*n_pos - bn*n_neg, biasB = n_pos - n_neg  (bias row t=2 -> t^g = n)
// t = max(2|x|,1e-12), s = sign(x), L = log2(t), g = log2(n_param).
// Inner loop (wd = wp-wn staged): u = ep-en; B += s*u; A += s*(wp*u + wd*en).
// R18: single staging episode per block (RPC=64, 64 KiB LDS, 2 blocks/CU):
//   barrier pairs 2->1, one uninterrupted 64-r-step trans stretch.

#define N_IN 1024
#define N_OUT 512
#define NB 128
#define Z 16            // r-split across grid.z (64 rows per block)
#define RPC 64          // rows per block, staged once
#define JT 32
#define BT 64

typedef float v2f __attribute__((ext_vector_type(2)));
typedef _Float16 h2 __attribute__((ext_vector_type(2)));
typedef _Float16 h4 __attribute__((ext_vector_type(4)));

// ws layout: float[0..255] tile-max slots (slot = jx*16+bz);
//   A partials (half) at ws+1024: [Z][NB][N_OUT] halfs = 2 MiB; B right after.
#define PLEN (Z * NB * N_OUT)   // halfs per array

__launch_bounds__(256, 2)
__global__ void memristor_mainAB(const float* __restrict__ x,
                                 const float* __restrict__ wp,
                                 const float* __restrict__ wn,
                                 const float* __restrict__ npar,
                                 float* __restrict__ ws) {
    // Wg[r][arr][grp][4]: arr 0=wp, 1=wd=wp-wn, 2=gp, 3=gn; grp XOR-swizzled by r&7
    __shared__ float Wg[RPC][4][8][4];    // 32 KiB
    __shared__ float Lx[RPC][BT][2];      // 32 KiB: (L, s), r-major

    const int tid = threadIdx.x;
    const int jx = blockIdx.x, by = blockIdx.y, bz = blockIdx.z;
    const int j0 = jx * JT;
    const int b0 = by * BT;
    const int rbase = bz * RPC;

    const int tj2 = tid & 15;       // j pair: j = j0 + tj2*2 (+0/1)
    const int bl0 = (tid >> 4) * 4; // 4 b rows per thread
    const int g8  = tj2 >> 1;       // Wg group
    const int sub = (tj2 & 1) * 2;  // float2 within group

    v2f accA[4], accB[4];
    #pragma unroll
    for (int i = 0; i < 4; ++i) { accA[i] = (v2f){0.f, 0.f}; accB[i] = (v2f){0.f, 0.f}; }
    float m_w = 0.0f;               // tile weight max (free: data already in regs)

    // ---------------- single staging episode ----------------
    {   // stage x: 64 b x 64 r; 16 r per thread (4 float4)
        int bl = tid & 63;          // b row
        int rq = tid >> 6;          // 0..3 -> r block of 16
        const float* xrow = &x[(b0 + bl) * N_IN + rbase + rq * 16];
        #pragma unroll
        for (int v4 = 0; v4 < 4; ++v4) {
            float4 v = *(const float4*)&xrow[v4 * 4];
            float vv[4] = {v.x, v.y, v.z, v.w};
            #pragma unroll
            for (int k = 0; k < 4; ++k) {
                float val = vv[k];
                float s = (val > 0.f) ? 1.f : ((val < 0.f) ? -1.f : 0.f);
                float t = fmaxf(2.f * fabsf(val), 1e-12f);
                Lx[rq * 16 + v4 * 4 + k][bl][0] = __builtin_amdgcn_logf(t);   // log2
                Lx[rq * 16 + v4 * 4 + k][bl][1] = s;
            }
        }
    }
    #pragma unroll
    for (int it = 0; it < 2; ++it) {   // stage weights: 64 r-rows x 32 j-cols
        int rr = (tid >> 3) + it * 32;  // 0..63
        int cg = tid & 7;               // 0..7
        int pg = cg ^ (rr & 7);         // XOR swizzle
        {
            const float* prow = &wp[(rbase + rr) * N_OUT + j0 + cg * 4];
            const float* nrow = &wn[(rbase + rr) * N_OUT + j0 + cg * 4];
            float4 pa = *(const float4*)&prow[0];
            float4 na = *(const float4*)&nrow[0];
            *(float4*)&Wg[rr][0][pg][0] = pa;
            *(float4*)&Wg[rr][1][pg][0] = make_float4(pa.x - na.x, pa.y - na.y,
                                                      pa.z - na.z, pa.w - na.w);
            m_w = fmaxf(m_w, fmaxf(fmaxf(pa.x, pa.y), fmaxf(pa.z, pa.w)));
            m_w = fmaxf(m_w, fmaxf(fmaxf(na.x, na.y), fmaxf(na.z, na.w)));
        }
        {
            const float* grow = &npar[(rbase + rr) * (2 * N_OUT) + 2 * j0 + cg * 8];
            float4 f0 = *(const float4*)&grow[0];    // p0 n0 p1 n1
            float4 f1 = *(const float4*)&grow[4];    // p2 n2 p3 n3
            *(float4*)&Wg[rr][2][pg][0] = make_float4(
                __builtin_amdgcn_logf(f0.x), __builtin_amdgcn_logf(f0.z),
                __builtin_amdgcn_logf(f1.x), __builtin_amdgcn_logf(f1.z));
            *(float4*)&Wg[rr][3][pg][0] = make_float4(
                __builtin_amdgcn_logf(f0.y), __builtin_amdgcn_logf(f0.w),
                __builtin_amdgcn_logf(f1.y), __builtin_amdgcn_logf(f1.w));
        }
    }
    __syncthreads();

    // ---------------- compute: 64 uninterrupted r-steps ----------------
    #pragma unroll 8
    for (int r = 0; r < RPC; ++r) {
        const float* wbase = &Wg[r][0][g8 ^ (r & 7)][sub];
        v2f w_p = *(const v2f*)&wbase[0];
        v2f w_d = *(const v2f*)&wbase[32];    // arr stride = 8 grp * 4 = 32 floats
        v2f g_p = *(const v2f*)&wbase[64];
        v2f g_n = *(const v2f*)&wbase[96];
        float4 l01 = *(const float4*)&Lx[r][bl0][0];       // (L0,s0,L1,s1)
        float4 l23 = *(const float4*)&Lx[r][bl0 + 2][0];   // (L2,s2,L3,s3)
        float Lv[4] = {l01.x, l01.z, l23.x, l23.z};
        float Sv[4] = {l01.y, l01.w, l23.y, l23.w};

        #pragma unroll
        for (int ib = 0; ib < 4; ++ib) {
            const float L = Lv[ib], s = Sv[ib];
            v2f ap = L * g_p;                 // v_pk_mul
            v2f an = L * g_n;
            v2f ep, en;
            ep.x = __builtin_amdgcn_exp2f(ap.x); ep.y = __builtin_amdgcn_exp2f(ap.y);
            en.x = __builtin_amdgcn_exp2f(an.x); en.y = __builtin_amdgcn_exp2f(an.y);
            v2f u = ep - en;                  // v_pk_add
            accB[ib] += s * u;                // v_pk_fma
            v2f v = w_p * u + w_d * en;       // pk_mul + pk_fma
            accA[ib] += s * v;
        }
    }

    // ---- write A/B partials as f16 (h2 per brow per array) ----
    {
        _Float16* hA = (_Float16*)(ws + 1024);
        _Float16* hB = hA + PLEN;
        size_t base = (size_t)bz * (NB * N_OUT) + (b0 + bl0) * N_OUT + j0 + tj2 * 2;
        #pragma unroll
        for (int ib = 0; ib < 4; ++ib) {
            h2 ha = {(_Float16)accA[ib].x, (_Float16)accA[ib].y};
            h2 hb = {(_Float16)accB[ib].x, (_Float16)accB[ib].y};
            *(h2*)&hA[base + (size_t)ib * N_OUT] = ha;
            *(h2*)&hB[base + (size_t)ib * N_OUT] = hb;
        }
    }

    // ---- tile weight-max slot (one writer set: by==0) ----
    if (by == 0) {
        __syncthreads();                 // all Lx reads done; safe to alias
        float* qred = &Lx[0][0][0];
        #pragma unroll
        for (int off = 32; off; off >>= 1) m_w = fmaxf(m_w, __shfl_xor(m_w, off));
        if ((tid & 63) == 0) qred[tid >> 6] = m_w;
        __syncthreads();
        if (tid == 0)
            ws[jx * Z + bz] = fmaxf(fmaxf(qred[0], qred[1]), fmaxf(qred[2], qred[3]));
    }
}

__global__ void reduce_combine(const float* __restrict__ ws,
                               const float* __restrict__ bp,
                               const float* __restrict__ bn,
                               const float* __restrict__ npar,
                               float* __restrict__ out) {
    const int tid = threadIdx.x;          // 64 threads (1 wave)
    const int g = blockIdx.x * 64 + tid;  // float4-of-output index, 0..16383

    // q = max(256 tile slots, bias weights) / 9 — single-wave reduce
    float mm = fmaxf(fmaxf(ws[tid], ws[tid + 64]),
                     fmaxf(ws[tid + 128], ws[tid + 192]));
    {
        const float4* b4 = (const float4*)&bp[tid * 8];
        const float4* c4 = (const float4*)&bn[tid * 8];
        float4 p0 = b4[0], p1 = b4[1], q0 = c4[0], q1 = c4[1];
        mm = fmaxf(mm, fmaxf(fmaxf(p0.x, p0.y), fmaxf(p0.z, p0.w)));
        mm = fmaxf(mm, fmaxf(fmaxf(p1.x, p1.y), fmaxf(p1.z, p1.w)));
        mm = fmaxf(mm, fmaxf(fmaxf(q0.x, q0.y), fmaxf(q0.z, q0.w)));
        mm = fmaxf(mm, fmaxf(fmaxf(q1.x, q1.y), fmaxf(q1.z, q1.w)));
    }
    #pragma unroll
    for (int off = 32; off; off >>= 1) mm = fmaxf(mm, __shfl_xor(mm, off));
    const float q = mm * (1.0f / 9.0f);

    const h4* hA = (const h4*)((const _Float16*)(ws + 1024));
    const h4* hB = hA + PLEN / 4;
    float ax = 0.f, ay = 0.f, az = 0.f, aw = 0.f;
    float bx = 0.f, byy = 0.f, bz2 = 0.f, bw = 0.f;
    #pragma unroll
    for (int z = 0; z < Z; ++z) {
        h4 va = hA[(size_t)z * (NB * N_OUT / 4) + g];
        h4 vb = hB[(size_t)z * (NB * N_OUT / 4) + g];
        ax += (float)va.x; ay += (float)va.y; az += (float)va.z; aw += (float)va.w;
        bx += (float)vb.x; byy += (float)vb.y; bz2 += (float)vb.z; bw += (float)vb.w;
    }
    const int j = (g * 4) & (N_OUT - 1);
    float4 bpv = *(const float4*)&bp[j];
    float4 bnv = *(const float4*)&bn[j];
    const float* nrow = &npar[N_IN * (2 * N_OUT) + 2 * j];
    float4 n0 = *(const float4*)&nrow[0];     // (np0,nn0,np1,nn1)
    float4 n1 = *(const float4*)&nrow[4];     // (np2,nn2,np3,nn3)
    float y0 = 0.5f * (ax + bpv.x * n0.x - bnv.x * n0.y + q * (bx  + n0.x - n0.y));
    float y1 = 0.5f * (ay + bpv.y * n0.z - bnv.y * n0.w + q * (byy + n0.z - n0.w));
    float y2 = 0.5f * (az + bpv.z * n1.x - bnv.z * n1.y + q * (bz2 + n1.x - n1.y));
    float y3 = 0.5f * (aw + bpv.w * n1.z - bnv.w * n1.w + q * (bw  + n1.z - n1.w));
    ((float4*)out)[g] = make_float4(y0, y1, y2, y3);
}

extern "C" void kernel_launch(void* const* d_in, const int* in_sizes, int n_in,
                              void* d_out, int out_size, void* d_ws, size_t ws_size,
                              hipStream_t stream) {
    const float* x    = (const float*)d_in[0];
    const float* wp   = (const float*)d_in[1];
    const float* wn   = (const float*)d_in[2];
    const float* bp   = (const float*)d_in[3];
    const float* bn   = (const float*)d_in[4];
    const float* npar = (const float*)d_in[5];
    float* out = (float*)d_out;
    float* ws  = (float*)d_ws;   // 256 slots + 4 MiB f16 A/B partials

    dim3 grid(N_OUT / JT, NB / BT, Z);   // (16,2,16) = 512 blocks, 2/CU
    memristor_mainAB<<<grid, 256, 0, stream>>>(x, wp, wn, npar, ws);

    reduce_combine<<<(NB * N_OUT / 4) / 64, 64, 0, stream>>>(ws, bp, bn, npar, out);
}